// Round 1
// baseline (7133.955 us; speedup 1.0000x reference)
//
#include <hip/hip_runtime.h>

// SNN: two recurrent LIF layers + linear readout.
// B=256, T=100, F=256, H=1024, O=8. All fp32 (round 1: correctness + baseline).

#define SNN_B 256
#define SNN_T 100
#define SNN_F 256
#define SNN_H 1024
#define SNN_O 8

#define ALPHA 0.9048374180359595f  // exp(-0.1)
#define BETA  0.8187307530779818f  // exp(-0.2)

// ---------------------------------------------------------------------------
// Generic fp32 GEMM: C[M,N] = A[M,K] @ B[K,N], all row-major.
// 64x64 tile, BK=16, 256 threads, 4x4 micro-tile.
// ---------------------------------------------------------------------------
__global__ __launch_bounds__(256) void gemm_f32(
    const float* __restrict__ A, const float* __restrict__ Bm,
    float* __restrict__ C, int M, int N, int K)
{
    __shared__ float As[16][68];   // [k][m], padded: 68 words => 2-way max
    __shared__ float Bs[16][64];   // [k][n]

    const int tid = threadIdx.x;
    const int m0 = blockIdx.y * 64;
    const int n0 = blockIdx.x * 64;
    const int tm = tid >> 4;          // 0..15
    const int tn = tid & 15;          // 0..15

    const int lrowA = tid >> 2;       // 0..63
    const int lkA   = (tid & 3) * 4;  // 0,4,8,12
    const int lkB   = tid >> 4;       // 0..15
    const int lnB   = (tid & 15) * 4; // 0..60

    float acc[4][4] = {};

    for (int k0 = 0; k0 < K; k0 += 16) {
        float4 a = *(const float4*)&A[(size_t)(m0 + lrowA) * K + k0 + lkA];
        As[lkA + 0][lrowA] = a.x;
        As[lkA + 1][lrowA] = a.y;
        As[lkA + 2][lrowA] = a.z;
        As[lkA + 3][lrowA] = a.w;
        *(float4*)&Bs[lkB][lnB] =
            *(const float4*)&Bm[(size_t)(k0 + lkB) * N + n0 + lnB];
        __syncthreads();
        #pragma unroll
        for (int k = 0; k < 16; ++k) {
            float4 av = *(const float4*)&As[k][tm * 4];
            float4 bv = *(const float4*)&Bs[k][tn * 4];
            float am[4] = {av.x, av.y, av.z, av.w};
            float bn[4] = {bv.x, bv.y, bv.z, bv.w};
            #pragma unroll
            for (int i = 0; i < 4; ++i)
                #pragma unroll
                for (int j = 0; j < 4; ++j)
                    acc[i][j] = fmaf(am[i], bn[j], acc[i][j]);
        }
        __syncthreads();
    }

    #pragma unroll
    for (int i = 0; i < 4; ++i) {
        float4 o = make_float4(acc[i][0], acc[i][1], acc[i][2], acc[i][3]);
        *(float4*)&C[(size_t)(m0 + tm * 4 + i) * N + n0 + tn * 4] = o;
    }
}

// ---------------------------------------------------------------------------
// One LIF time step for one layer.
//   rec        = spk_{t-1} @ R           (zeros at t==0)
//   spk_t      = (pot_{t-1} - 1 > 0)
//   cur_t      = ALPHA*cur_{t-1} + h[:,t,:] + rec
//   pot_t      = (BETA*pot_{t-1} + cur_t) * (1 - spk_t)
// Grid (16 col-tiles, 16 batch-tiles), 256 threads, tile 16 batch x 64 cols,
// 2x2 per-thread micro-tile, K chunked by 64 through LDS.
// ---------------------------------------------------------------------------
__global__ __launch_bounds__(256) void lif_step(
    const float* __restrict__ hbuf,  // [B*T*H]
    const float* __restrict__ R,     // [H*H]
    float* __restrict__ s_reg,       // [B*T*H] spikes (read t-1, write t)
    float* __restrict__ v_reg,       // [B*T*H] potentials (write t)
    float* __restrict__ cur,         // [B*H]
    float* __restrict__ pot,         // [B*H]
    int t)
{
    __shared__ float S_T[64][16];    // [k][b]
    __shared__ float R_s[64][64];    // [k][j]

    const int tid = threadIdx.x;
    const int j0 = blockIdx.x * 64;
    const int b0 = blockIdx.y * 16;
    const int bg = tid >> 5;         // 0..7  -> batch pair
    const int cg = tid & 31;         // 0..31 -> col pair

    float acc[2][2] = {{0.f, 0.f}, {0.f, 0.f}};

    if (t > 0) {
        const int lb = tid >> 4;         // 0..15
        const int lk = (tid & 15) * 4;   // 0..60
        const int lc = (tid & 15) * 4;   // 0..60
        for (int k0 = 0; k0 < SNN_H; k0 += 64) {
            // spikes of step t-1, transposed into LDS [k][b]
            float4 s = *(const float4*)&s_reg[((size_t)(b0 + lb) * SNN_T + (t - 1)) * SNN_H + k0 + lk];
            S_T[lk + 0][lb] = s.x;
            S_T[lk + 1][lb] = s.y;
            S_T[lk + 2][lb] = s.z;
            S_T[lk + 3][lb] = s.w;
            #pragma unroll
            for (int i = 0; i < 4; ++i) {
                *(float4*)&R_s[lb + i * 16][lc] =
                    *(const float4*)&R[(size_t)(k0 + lb + i * 16) * SNN_H + j0 + lc];
            }
            __syncthreads();
            #pragma unroll
            for (int kk = 0; kk < 64; ++kk) {
                float2 sv = *(const float2*)&S_T[kk][bg * 2];
                float2 rv = *(const float2*)&R_s[kk][cg * 2];
                acc[0][0] = fmaf(sv.x, rv.x, acc[0][0]);
                acc[0][1] = fmaf(sv.x, rv.y, acc[0][1]);
                acc[1][0] = fmaf(sv.y, rv.x, acc[1][0]);
                acc[1][1] = fmaf(sv.y, rv.y, acc[1][1]);
            }
            __syncthreads();
        }
    }

    #pragma unroll
    for (int i = 0; i < 2; ++i) {
        const int b = b0 + bg * 2 + i;
        #pragma unroll
        for (int jj = 0; jj < 2; ++jj) {
            const int j = j0 + cg * 2 + jj;
            const size_t sidx = (size_t)b * SNN_H + j;
            const size_t tidx = ((size_t)b * SNN_T + t) * SNN_H + j;
            float c_old = 0.f, p_old = 0.f;
            if (t > 0) { c_old = cur[sidx]; p_old = pot[sidx]; }
            float spk = ((p_old - 1.0f) > 0.0f) ? 1.0f : 0.0f;
            float c_new = fmaf(ALPHA, c_old, hbuf[tidx]) + acc[i][jj];
            float p_new = fmaf(BETA, p_old, c_new) * (1.0f - spk);
            cur[sidx] = c_new;
            pot[sidx] = p_new;
            s_reg[tidx] = spk;
            v_reg[tidx] = p_new;
        }
    }
}

// ---------------------------------------------------------------------------
// Readout GEMM: h3[row, o] = sum_k s2[row, k] * Wout[k, o], row = b*T + t.
// Thread per (row, o); 8 lanes share a row (L1 broadcast).
// ---------------------------------------------------------------------------
__global__ __launch_bounds__(256) void readout_gemm(
    const float* __restrict__ s2in, const float* __restrict__ Wout,
    float* __restrict__ h3)
{
    const int gid = blockIdx.x * 256 + threadIdx.x;
    const int row = gid >> 3;
    const int o = gid & 7;
    const float* srow = s2in + (size_t)row * SNN_H;
    float acc = 0.f;
    for (int k = 0; k < SNN_H; k += 4) {
        float4 s = *(const float4*)&srow[k];
        acc = fmaf(s.x, Wout[(k + 0) * SNN_O + o], acc);
        acc = fmaf(s.y, Wout[(k + 1) * SNN_O + o], acc);
        acc = fmaf(s.z, Wout[(k + 2) * SNN_O + o], acc);
        acc = fmaf(s.w, Wout[(k + 3) * SNN_O + o], acc);
    }
    h3[(size_t)row * SNN_O + o] = acc;
}

// ---------------------------------------------------------------------------
// Readout linear scan: out[b,0,:]=0; cur=a*cur+h3; pot=b*pot+cur; out[b,t+1,:]=pot
// ---------------------------------------------------------------------------
__global__ __launch_bounds__(256) void readout_scan(
    const float* __restrict__ h3, float* __restrict__ out)
{
    const int gid = blockIdx.x * 256 + threadIdx.x;  // 2048 = B*O
    const int b = gid >> 3;
    const int o = gid & 7;
    float c = 0.f, p = 0.f;
    out[((size_t)b * (SNN_T + 1) + 0) * SNN_O + o] = 0.f;
    for (int t = 0; t < SNN_T; ++t) {
        c = fmaf(ALPHA, c, h3[((size_t)b * SNN_T + t) * SNN_O + o]);
        p = fmaf(BETA, p, c);
        out[((size_t)b * (SNN_T + 1) + t + 1) * SNN_O + o] = p;
    }
}

// ---------------------------------------------------------------------------
extern "C" void kernel_launch(void* const* d_in, const int* in_sizes, int n_in,
                              void* d_out, int out_size, void* d_ws, size_t ws_size,
                              hipStream_t stream)
{
    const float* X    = (const float*)d_in[0];  // [B,T,F]
    const float* W0   = (const float*)d_in[1];  // [F,H]
    const float* W1   = (const float*)d_in[2];  // [H,H]
    const float* R0   = (const float*)d_in[3];  // [H,H]
    const float* R1   = (const float*)d_in[4];  // [H,H]
    const float* Wout = (const float*)d_in[5];  // [H,O]

    const size_t BT_H = (size_t)SNN_B * SNN_T * SNN_H;  // 26,214,400
    float* out = (float*)d_out;                          // [B,T+1,O]
    float* s1  = out + (size_t)SNN_B * (SNN_T + 1) * SNN_O;  // +206848
    float* s2  = s1 + BT_H;
    float* v1  = s2 + BT_H;
    float* v2  = v1 + BT_H;

    float* ws   = (float*)d_ws;
    float* hbuf = ws;                       // [B*T*H] (h1, then reused for h2)
    float* curb = hbuf + BT_H;              // [B*H]
    float* potb = curb + (size_t)SNN_B * SNN_H;
    float* h3   = potb + (size_t)SNN_B * SNN_H;  // [B*T*O]

    const int M = SNN_B * SNN_T;  // 25600

    // h1 = X @ W0
    gemm_f32<<<dim3(SNN_H / 64, M / 64), 256, 0, stream>>>(X, W0, hbuf, M, SNN_H, SNN_F);

    // layer-1 scan
    for (int t = 0; t < SNN_T; ++t)
        lif_step<<<dim3(SNN_H / 64, SNN_B / 16), 256, 0, stream>>>(
            hbuf, R0, s1, v1, curb, potb, t);

    // h2 = s1 @ W1 (reuse hbuf)
    gemm_f32<<<dim3(SNN_H / 64, M / 64), 256, 0, stream>>>(s1, W1, hbuf, M, SNN_H, SNN_H);

    // layer-2 scan
    for (int t = 0; t < SNN_T; ++t)
        lif_step<<<dim3(SNN_H / 64, SNN_B / 16), 256, 0, stream>>>(
            hbuf, R1, s2, v2, curb, potb, t);

    // readout
    readout_gemm<<<(M * SNN_O) / 256, 256, 0, stream>>>(s2, Wout, h3);
    readout_scan<<<(SNN_B * SNN_O) / 256, 256, 0, stream>>>(h3, out);
}